// Round 8
// baseline (635.112 us; speedup 1.0000x reference)
//
#include <hip/hip_runtime.h>
#include <hip/hip_fp16.h>
#include <math.h>

#define N_NODES 50000
#define N_EDGES 800000
#define HD 128          // H*D = 4*32
#define GG 1024
#define NEG_SLOPE 0.2f
#define SCAN_B 1024
#define NB ((N_NODES + SCAN_B - 1) / SCAN_B)   // 49

typedef __attribute__((ext_vector_type(8))) short bf16x8;
typedef __attribute__((ext_vector_type(4))) float f32x4;

__device__ __forceinline__ unsigned short f2bf(float v) {
    unsigned u = __float_as_uint(v);
    u += 0x7fff + ((u >> 16) & 1);       // round-to-nearest-even
    return (unsigned short)(u >> 16);
}
__device__ __forceinline__ float bf2f(unsigned short s) {
    return __uint_as_float((unsigned)s << 16);
}
__device__ __forceinline__ void h8_to_f(const uint4& r, float4& v0, float4& v1) {
    const __half2* h = (const __half2*)&r;
    float2 a = __half22float2(h[0]), b = __half22float2(h[1]);
    float2 c = __half22float2(h[2]), d = __half22float2(h[3]);
    v0 = make_float4(a.x, a.y, b.x, b.y);
    v1 = make_float4(c.x, c.y, d.x, d.y);
}

// ------------------------- fused split-bf16 conversion (x + all 3 W pairs)
#define XTOT (N_NODES * 64)
#define WTOT (256 * 64 + 2 * 256 * 128)
__global__ void convert_all(const float* __restrict__ x,
                            const float* __restrict__ W0l, const float* __restrict__ W0r,
                            const float* __restrict__ W1l, const float* __restrict__ W1r,
                            const float* __restrict__ W2l, const float* __restrict__ W2r,
                            unsigned short* __restrict__ Xh, unsigned short* __restrict__ Xl,
                            unsigned short* __restrict__ Wth, unsigned short* __restrict__ Wtl)
{
    int t = blockIdx.x * 256 + threadIdx.x;
    if (t < XTOT) {
        float v = x[t];
        unsigned short hi = f2bf(v);
        unsigned short lo = f2bf(v - bf2f(hi));
        Xh[t] = hi; Xl[t] = lo;
        return;
    }
    t -= XTOT;
    if (t >= WTOT) return;
    int l, local, K;
    const float* Wl; const float* Wr;
    if (t < 256 * 64)                  { l = 0; local = t;                    K = 64;  Wl = W0l; Wr = W0r; }
    else if (t < 256 * 64 + 256 * 128) { l = 1; local = t - 256 * 64;         K = 128; Wl = W1l; Wr = W1r; }
    else                               { l = 2; local = t - 256*64 - 256*128; K = 128; Wl = W2l; Wr = W2r; }
    int c = local / K, k = local - c * K;
    float v = (c < 128) ? Wl[(size_t)k * 128 + c] : Wr[(size_t)k * 128 + (c - 128)];
    unsigned short hi = f2bf(v);
    unsigned short lo = f2bf(v - bf2f(hi));
    Wth[l * 256 * 128 + local] = hi;
    Wtl[l * 256 * 128 + local] = lo;
}

// --------------------------------------------------- MFMA split-bf16 dual GEMM v4
// B held in REGISTERS for the whole kernel (loaded once per wave); block = 96 rows,
// wave = 64 cols; loop over 6 m-tiles with depth-1 A prefetch. No LDS, no barriers.
template<int K>
__launch_bounds__(256, 2)
__global__ void gemm_mfma(const unsigned short* __restrict__ Xh, const unsigned short* __restrict__ Xl,
                          const unsigned short* __restrict__ Wth, const unsigned short* __restrict__ Wtl,
                          const float* __restrict__ bl, const float* __restrict__ br,
                          __half* __restrict__ Cl16, float* __restrict__ Cr, int n)
{
    constexpr int NCH = K / 32;
    constexpr int MT = 6;                 // 96 rows / 16
    const int tid  = threadIdx.x;
    const int wave = tid >> 6;
    const int lane = tid & 63;
    const int quad = lane >> 4;
    const int l15  = lane & 15;
    const int row0 = blockIdx.x * 96;

    // ---- B resident in registers: NCH*4 hi + NCH*4 lo fragments
    bf16x8 bh[NCH][4], bo[NCH][4];
    #pragma unroll
    for (int ch = 0; ch < NCH; ch++)
        #pragma unroll
        for (int nt = 0; nt < 4; nt++) {
            const size_t wo = (size_t)(wave * 64 + nt * 16 + l15) * K + ch * 32 + quad * 8;
            bh[ch][nt] = *(const bf16x8*)(Wth + wo);
            bo[ch][nt] = *(const bf16x8*)(Wtl + wo);
        }

    // A fragment loader for one 16-row m-tile
    auto arow = [&](int mt) -> size_t {
        int r = row0 + mt * 16 + l15;
        if (r >= n) r = n - 1;
        return (size_t)r * K + quad * 8;
    };

    bf16x8 ah[NCH], al[NCH], nah[NCH], nal[NCH];
    {
        const size_t ao = arow(0);
        #pragma unroll
        for (int ch = 0; ch < NCH; ch++) {
            ah[ch] = *(const bf16x8*)(Xh + ao + ch * 32);
            al[ch] = *(const bf16x8*)(Xl + ao + ch * 32);
        }
    }

    const bool isL = (wave < 2);
    const int colbase = (wave & 1) * 64;
    const float* bias = isL ? bl : br;
    float bv[4];
    #pragma unroll
    for (int nt = 0; nt < 4; nt++) bv[nt] = bias[colbase + nt * 16 + l15];

    #pragma unroll
    for (int mt = 0; mt < MT; mt++) {
        if (mt + 1 < MT) {
            const size_t ao = arow(mt + 1);
            #pragma unroll
            for (int ch = 0; ch < NCH; ch++) {
                nah[ch] = *(const bf16x8*)(Xh + ao + ch * 32);
                nal[ch] = *(const bf16x8*)(Xl + ao + ch * 32);
            }
        }
        f32x4 acc[4];
        #pragma unroll
        for (int nt = 0; nt < 4; nt++) acc[nt] = (f32x4){0.f, 0.f, 0.f, 0.f};
        #pragma unroll
        for (int ch = 0; ch < NCH; ch++)
            #pragma unroll
            for (int nt = 0; nt < 4; nt++) {
                acc[nt] = __builtin_amdgcn_mfma_f32_16x16x32_bf16(ah[ch], bh[ch][nt], acc[nt], 0, 0, 0);
                acc[nt] = __builtin_amdgcn_mfma_f32_16x16x32_bf16(ah[ch], bo[ch][nt], acc[nt], 0, 0, 0);
                acc[nt] = __builtin_amdgcn_mfma_f32_16x16x32_bf16(al[ch], bh[ch][nt], acc[nt], 0, 0, 0);
            }
        // store this m-tile (C/D layout: col=lane&15, row=quad*4+reg)
        #pragma unroll
        for (int nt = 0; nt < 4; nt++) {
            const int col = colbase + nt * 16 + l15;
            #pragma unroll
            for (int r = 0; r < 4; r++) {
                const int row = row0 + mt * 16 + quad * 4 + r;
                if (row < n) {
                    const float v = acc[nt][r] + bv[nt];
                    if (isL) Cl16[(size_t)row * 128 + col] = __float2half_rn(v);
                    else     Cr  [(size_t)row * 128 + col] = v;
                }
            }
        }
        if (mt + 1 < MT) {
            #pragma unroll
            for (int ch = 0; ch < NCH; ch++) { ah[ch] = nah[ch]; al[ch] = nal[ch]; }
        }
    }
}

// ---------------------------------------------------------------- CSR build
__global__ void deg_gptr(const int* __restrict__ dst, int* __restrict__ deg,
                         const int* __restrict__ batch, int* __restrict__ gptr)
{
    int i = blockIdx.x * 256 + threadIdx.x;
    if (i < N_EDGES) atomicAdd(&deg[dst[i]], 1);
    if (i <= N_NODES) {
        if (i == 0) {
            for (int g = 0; g <= batch[0]; g++) gptr[g] = 0;
        } else if (i == N_NODES) {
            for (int g = batch[N_NODES - 1] + 1; g <= GG; g++) gptr[g] = N_NODES;
        } else {
            int b0 = batch[i - 1], b1 = batch[i];
            for (int g = b0 + 1; g <= b1; g++) gptr[g] = i;
        }
    }
}

__launch_bounds__(SCAN_B)
__global__ void scan_block(const int* __restrict__ deg, int* __restrict__ rowptr,
                           int* __restrict__ btot)
{
    __shared__ int s[SCAN_B];
    const int tid = threadIdx.x;
    const int i = blockIdx.x * SCAN_B + tid;
    int v = (i < N_NODES) ? deg[i] : 0;
    s[tid] = v;
    __syncthreads();
    for (int off = 1; off < SCAN_B; off <<= 1) {
        int t = (tid >= off) ? s[tid - off] : 0;
        __syncthreads();
        s[tid] += t;
        __syncthreads();
    }
    if (i < N_NODES) rowptr[i] = s[tid] - v;
    if (tid == SCAN_B - 1) btot[blockIdx.x] = s[SCAN_B - 1];
}

__global__ void scan_btot(const int* __restrict__ btot, int* __restrict__ boff) {
    const int t = threadIdx.x;      // 64 threads
    int v = (t < NB) ? btot[t] : 0;
    const int orig = v;
    #pragma unroll
    for (int off = 1; off < 64; off <<= 1) {
        int u = __shfl_up(v, off);
        if (t >= off) v += u;
    }
    if (t < NB) boff[t] = v - orig;
    if (t == NB - 1) boff[NB] = v;
}

__global__ void scan_add(const int* __restrict__ boff, int* __restrict__ rowptr,
                         int* __restrict__ cursor)
{
    int i = blockIdx.x * 256 + threadIdx.x;
    if (i < N_NODES) {
        int r = rowptr[i] + boff[i >> 10];
        rowptr[i] = r;
        cursor[i] = r;
    }
    if (i == N_NODES) rowptr[N_NODES] = boff[NB];
}

__global__ void scatter_csr(const int* __restrict__ src, const int* __restrict__ dst,
                            int* __restrict__ cursor, int* __restrict__ csr_src)
{
    int e = blockIdx.x * 256 + threadIdx.x;
    if (e >= N_EDGES) return;
    int pos = atomicAdd(&cursor[dst[e]], 1);
    csr_src[pos] = src[e];
}

// ------------------------------------------------- fused per-node attention v3
// one wave per dst node, EIGHT edges in flight (8 lanes x 16 dims each).
// score reduce = 1 shuffle; branchless online softmax (no ballot, no branch).
__launch_bounds__(256)
__global__ void node_attn(const __half* __restrict__ xl16, const float* __restrict__ xr,
                          const int* __restrict__ rowptr, const int* __restrict__ csr_src,
                          const float* __restrict__ att, const float* __restrict__ bvec,
                          unsigned short* __restrict__ Hh, unsigned short* __restrict__ Hl)
{
    const int node = (blockIdx.x * 256 + threadIdx.x) >> 6;
    const int lane = threadIdx.x & 63;
    if (node >= N_NODES) return;
    const int eslot = lane >> 3;         // edge slot 0..7
    const int lj    = lane & 7;          // dims lj*16 .. lj*16+15 (head = lj>>1)

    const float* xrp = xr + (size_t)node * HD + lj * 16;
    const float4 xr0 = *(const float4*)(xrp + 0);
    const float4 xr1 = *(const float4*)(xrp + 4);
    const float4 xr2 = *(const float4*)(xrp + 8);
    const float4 xr3 = *(const float4*)(xrp + 12);
    const float4 aw0 = *(const float4*)(att + lj * 16 + 0);
    const float4 aw1 = *(const float4*)(att + lj * 16 + 4);
    const float4 aw2 = *(const float4*)(att + lj * 16 + 8);
    const float4 aw3 = *(const float4*)(att + lj * 16 + 12);
    const int beg = rowptr[node];
    const int end = rowptr[node + 1];

    float m = -1e30f, l = 0.f;
    float4 A0 = {0,0,0,0}, A1 = {0,0,0,0}, A2 = {0,0,0,0}, A3 = {0,0,0,0};

    int i0 = beg + eslot;
    int s0 = (i0 < end) ? csr_src[i0] : 0;
    const uint4* rp = (const uint4*)(xl16 + (size_t)s0 * HD + lj * 16);
    uint4 c0 = rp[0], c1 = rp[1];

    for (int base = beg; base < end; base += 8) {
        const bool valid = (base + eslot) < end;
        uint4 n0 = c0, n1 = c1;
        if (base + 8 < end) {
            int e2 = base + 8 + eslot;
            int s2 = (e2 < end) ? csr_src[e2] : 0;
            const uint4* np = (const uint4*)(xl16 + (size_t)s2 * HD + lj * 16);
            n0 = np[0]; n1 = np[1];
        }
        float4 v0, v1, v2, v3;
        h8_to_f(c0, v0, v1);
        h8_to_f(c1, v2, v3);
        float t, p;
        t = v0.x + xr0.x; t = fmaxf(t, NEG_SLOPE * t); p  = t * aw0.x;
        t = v0.y + xr0.y; t = fmaxf(t, NEG_SLOPE * t); p += t * aw0.y;
        t = v0.z + xr0.z; t = fmaxf(t, NEG_SLOPE * t); p += t * aw0.z;
        t = v0.w + xr0.w; t = fmaxf(t, NEG_SLOPE * t); p += t * aw0.w;
        t = v1.x + xr1.x; t = fmaxf(t, NEG_SLOPE * t); p += t * aw1.x;
        t = v1.y + xr1.y; t = fmaxf(t, NEG_SLOPE * t); p += t * aw1.y;
        t = v1.z + xr1.z; t = fmaxf(t, NEG_SLOPE * t); p += t * aw1.z;
        t = v1.w + xr1.w; t = fmaxf(t, NEG_SLOPE * t); p += t * aw1.w;
        t = v2.x + xr2.x; t = fmaxf(t, NEG_SLOPE * t); p += t * aw2.x;
        t = v2.y + xr2.y; t = fmaxf(t, NEG_SLOPE * t); p += t * aw2.y;
        t = v2.z + xr2.z; t = fmaxf(t, NEG_SLOPE * t); p += t * aw2.z;
        t = v2.w + xr2.w; t = fmaxf(t, NEG_SLOPE * t); p += t * aw2.w;
        t = v3.x + xr3.x; t = fmaxf(t, NEG_SLOPE * t); p += t * aw3.x;
        t = v3.y + xr3.y; t = fmaxf(t, NEG_SLOPE * t); p += t * aw3.y;
        t = v3.z + xr3.z; t = fmaxf(t, NEG_SLOPE * t); p += t * aw3.z;
        t = v3.w + xr3.w; t = fmaxf(t, NEG_SLOPE * t); p += t * aw3.w;
        p += __shfl_xor(p, 1);           // head score (2 lanes per head)

        const float pe = valid ? p : -1e30f;
        const float mn = fmaxf(m, pe);
        const float sc = __expf(m - mn);
        const float w  = valid ? __expf(p - mn) : 0.f;
        l = l * sc + w;
        A0.x = A0.x * sc + w * v0.x; A0.y = A0.y * sc + w * v0.y;
        A0.z = A0.z * sc + w * v0.z; A0.w = A0.w * sc + w * v0.w;
        A1.x = A1.x * sc + w * v1.x; A1.y = A1.y * sc + w * v1.y;
        A1.z = A1.z * sc + w * v1.z; A1.w = A1.w * sc + w * v1.w;
        A2.x = A2.x * sc + w * v2.x; A2.y = A2.y * sc + w * v2.y;
        A2.z = A2.z * sc + w * v2.z; A2.w = A2.w * sc + w * v2.w;
        A3.x = A3.x * sc + w * v3.x; A3.y = A3.y * sc + w * v3.y;
        A3.z = A3.z * sc + w * v3.z; A3.w = A3.w * sc + w * v3.w;
        m = mn;
        c0 = n0; c1 = n1;
    }

    // merge the 8 edge-slot states: butterfly xor 8, 16, 32
    #pragma unroll
    for (int off = 8; off <= 32; off <<= 1) {
        const float mo = __shfl_xor(m, off);
        const float lo = __shfl_xor(l, off);
        float4 B0, B1, B2, B3;
        B0.x = __shfl_xor(A0.x, off); B0.y = __shfl_xor(A0.y, off);
        B0.z = __shfl_xor(A0.z, off); B0.w = __shfl_xor(A0.w, off);
        B1.x = __shfl_xor(A1.x, off); B1.y = __shfl_xor(A1.y, off);
        B1.z = __shfl_xor(A1.z, off); B1.w = __shfl_xor(A1.w, off);
        B2.x = __shfl_xor(A2.x, off); B2.y = __shfl_xor(A2.y, off);
        B2.z = __shfl_xor(A2.z, off); B2.w = __shfl_xor(A2.w, off);
        B3.x = __shfl_xor(A3.x, off); B3.y = __shfl_xor(A3.y, off);
        B3.z = __shfl_xor(A3.z, off); B3.w = __shfl_xor(A3.w, off);
        const float mm = fmaxf(m, mo);
        const float e1 = __expf(m - mm);
        const float e2 = __expf(mo - mm);
        l = l * e1 + lo * e2;
        A0.x = A0.x * e1 + B0.x * e2; A0.y = A0.y * e1 + B0.y * e2;
        A0.z = A0.z * e1 + B0.z * e2; A0.w = A0.w * e1 + B0.w * e2;
        A1.x = A1.x * e1 + B1.x * e2; A1.y = A1.y * e1 + B1.y * e2;
        A1.z = A1.z * e1 + B1.z * e2; A1.w = A1.w * e1 + B1.w * e2;
        A2.x = A2.x * e1 + B2.x * e2; A2.y = A2.y * e1 + B2.y * e2;
        A2.z = A2.z * e1 + B2.z * e2; A2.w = A2.w * e1 + B2.w * e2;
        A3.x = A3.x * e1 + B3.x * e2; A3.y = A3.y * e1 + B3.y * e2;
        A3.z = A3.z * e1 + B3.z * e2; A3.w = A3.w * e1 + B3.w * e2;
        m = mm;
    }

    if (eslot == 0) {
        const float inv = (l > 0.f) ? 1.f / l : 0.f;
        float o[16];
        const float* bb = bvec + lj * 16;
        o[0]=A0.x; o[1]=A0.y; o[2]=A0.z; o[3]=A0.w;
        o[4]=A1.x; o[5]=A1.y; o[6]=A1.z; o[7]=A1.w;
        o[8]=A2.x; o[9]=A2.y; o[10]=A2.z; o[11]=A2.w;
        o[12]=A3.x; o[13]=A3.y; o[14]=A3.z; o[15]=A3.w;
        uint4 ph[2], pl[2];
        unsigned* php = (unsigned*)ph;
        unsigned* plp = (unsigned*)pl;
        #pragma unroll
        for (int j = 0; j < 8; j++) {
            float u0 = o[2*j]   * inv + bb[2*j];
            float u1 = o[2*j+1] * inv + bb[2*j+1];
            u0 = (u0 > 0.f) ? u0 : expm1f(u0);
            u1 = (u1 > 0.f) ? u1 : expm1f(u1);
            unsigned short h0 = f2bf(u0), h1 = f2bf(u1);
            unsigned short q0 = f2bf(u0 - bf2f(h0)), q1 = f2bf(u1 - bf2f(h1));
            php[j] = (unsigned)h0 | ((unsigned)h1 << 16);
            plp[j] = (unsigned)q0 | ((unsigned)q1 << 16);
        }
        uint4* hp = (uint4*)(Hh + (size_t)node * HD + lj * 16);
        uint4* lp = (uint4*)(Hl + (size_t)node * HD + lj * 16);
        hp[0] = ph[0]; hp[1] = ph[1];
        lp[0] = pl[0]; lp[1] = pl[1];
    }
}

// ------------------------------------------ fused mean-pool + linear head
__launch_bounds__(256)
__global__ void pool_head(const unsigned short* __restrict__ Hh, const unsigned short* __restrict__ Hl,
                          const int* __restrict__ gptr, const float* __restrict__ Wh,
                          const float* __restrict__ bh, float* __restrict__ out)
{
    const int g = (blockIdx.x * 256 + threadIdx.x) >> 6;
    const int lane = threadIdx.x & 63;
    if (g >= GG) return;
    const int b0 = gptr[g], b1 = gptr[g + 1];
    const float2 w = *(const float2*)(Wh + lane * 2);
    float sx = 0.f, sy = 0.f;
    for (int i = b0; i < b1; i++) {
        const unsigned vh = *(const unsigned*)(Hh + (size_t)i * HD + lane * 2);
        const unsigned vl = *(const unsigned*)(Hl + (size_t)i * HD + lane * 2);
        sx += bf2f((unsigned short)(vh & 0xffff)) + bf2f((unsigned short)(vl & 0xffff));
        sy += bf2f((unsigned short)(vh >> 16))    + bf2f((unsigned short)(vl >> 16));
    }
    float d = sx * w.x + sy * w.y;
    d += __shfl_xor(d, 1);
    d += __shfl_xor(d, 2);
    d += __shfl_xor(d, 4);
    d += __shfl_xor(d, 8);
    d += __shfl_xor(d, 16);
    d += __shfl_xor(d, 32);
    if (lane == 0) out[g] = d / fmaxf((float)(b1 - b0), 1.f) + bh[0];
}

// ---------------------------------------------------------------- launch
extern "C" void kernel_launch(void* const* d_in, const int* in_sizes, int n_in,
                              void* d_out, int out_size, void* d_ws, size_t ws_size,
                              hipStream_t stream)
{
    const float* x     = (const float*)d_in[0];
    const int*   edge  = (const int*)d_in[1];
    const int*   batch = (const int*)d_in[2];
    const int*   src   = edge;
    const int*   dst   = edge + N_EDGES;
    const float* Wh    = (const float*)d_in[21];
    const float* bh    = (const float*)d_in[22];
    float* out = (float*)d_out;

    const size_t N128 = (size_t)N_NODES * HD;
    __half* xl16  = (__half*)d_ws;                      // N*128 fp16
    float* buf_xr = (float*)(xl16 + N128);              // N*128 f32
    unsigned short* Xh  = (unsigned short*)(buf_xr + N128);   // N*128 bf16
    unsigned short* Xl_ = Xh + N128;                    // N*128 bf16
    unsigned short* Wth = Xl_ + N128;                   // 3 * 256*128 bf16
    unsigned short* Wtl = Wth + 3 * 256 * 128;          // 3 * 256*128 bf16
    int* deg     = (int*)(Wtl + 3 * 256 * 128);         // N
    int* rowptr  = deg + N_NODES;                       // N+1
    int* cursor  = rowptr + N_NODES + 1;                // N
    int* csr_src = cursor + N_NODES;                    // E
    int* btot    = csr_src + N_EDGES;                   // NB
    int* boff    = btot + NB;                           // NB+1
    int* gptr    = boff + NB + 1;                       // G+1

    // ---- CSR + graph-boundary build (layer-invariant)
    hipMemsetAsync(deg, 0, (size_t)N_NODES * sizeof(int), stream);
    deg_gptr<<<(N_EDGES + 255) / 256, 256, 0, stream>>>(dst, deg, batch, gptr);
    scan_block<<<NB, SCAN_B, 0, stream>>>(deg, rowptr, btot);
    scan_btot<<<1, 64, 0, stream>>>(btot, boff);
    scan_add<<<(N_NODES + 256) / 256, 256, 0, stream>>>(boff, rowptr, cursor);
    scatter_csr<<<(N_EDGES + 255) / 256, 256, 0, stream>>>(src, dst, cursor, csr_src);

    // ---- fused input+weight split-bf16 conversion
    convert_all<<<(XTOT + WTOT + 255) / 256, 256, 0, stream>>>(
        x,
        (const float*)d_in[3],  (const float*)d_in[5],
        (const float*)d_in[9],  (const float*)d_in[11],
        (const float*)d_in[15], (const float*)d_in[17],
        Xh, Xl_, Wth, Wtl);

    const int gemm_grid = (N_NODES + 95) / 96;
    const int attn_grid = (N_NODES + 3) / 4;

    for (int l = 0; l < 3; l++) {
        const float* bl  = (const float*)d_in[4 + 6 * l];
        const float* br  = (const float*)d_in[6 + 6 * l];
        const float* att = (const float*)d_in[7 + 6 * l];
        const float* bb  = (const float*)d_in[8 + 6 * l];

        if (l == 0)
            gemm_mfma<64><<<gemm_grid, 256, 0, stream>>>(Xh, Xl_, Wth, Wtl,
                                                         bl, br, xl16, buf_xr, N_NODES);
        else
            gemm_mfma<128><<<gemm_grid, 256, 0, stream>>>(Xh, Xl_,
                                                          Wth + l * 256 * 128, Wtl + l * 256 * 128,
                                                          bl, br, xl16, buf_xr, N_NODES);
        node_attn<<<attn_grid, 256, 0, stream>>>(xl16, buf_xr, rowptr, csr_src,
                                                 att, bb, Xh, Xl_);
    }

    pool_head<<<GG / 4, 256, 0, stream>>>(Xh, Xl_, gptr, Wh, bh, out);
}